// Round 1
// baseline (10557.378 us; speedup 1.0000x reference)
//
#include <hip/hip_runtime.h>
#include <hip/hip_bf16.h>

#define BB 16
#define SS 512
#define VOCAB 32000
#define EMB 512
#define HID 1024
#define LAT 256

typedef __attribute__((ext_vector_type(8))) short bf16x8v;
typedef __attribute__((ext_vector_type(4))) float f32x4v;

__device__ __forceinline__ unsigned short f2b(float f) {
  unsigned int u = __float_as_uint(f);
  unsigned int r = (u + 0x7fffu + ((u >> 16) & 1u)) >> 16;
  return (unsigned short)r;
}

// ---------------- generic fp32 -> bf16 ----------------
__global__ __launch_bounds__(256) void k_f2b(const float* __restrict__ src,
                                             unsigned short* __restrict__ dst, int n) {
  int i = blockIdx.x * 256 + threadIdx.x;
  int stride = gridDim.x * 256;
  for (; i < n; i += stride) dst[i] = f2b(src[i]);
}

// ---------------- biases + counters ----------------
__global__ __launch_bounds__(256) void k_misc(const float* __restrict__ bih0, const float* __restrict__ bhh0,
                                              const float* __restrict__ bih1, const float* __restrict__ bhh1,
                                              float* __restrict__ bias0, float* __restrict__ bias1,
                                              unsigned int* __restrict__ cnt) {
  int i = blockIdx.x * 256 + threadIdx.x;
  if (i < HID) { bias0[i] = bih0[i] + bhh0[i]; bias1[i] = bih1[i] + bhh1[i]; }
  if (i < 2) cnt[i] = 0u;
}

// ---------------- hidden = z @ l2h_w + b, torch-reshape to [2][16][1024], bf16 ----------------
__global__ __launch_bounds__(256) void k_latent(const float* __restrict__ z, const float* __restrict__ w,
                                                const float* __restrict__ bvec, unsigned short* __restrict__ h0) {
  int idx = blockIdx.x * 256 + threadIdx.x;          // [0, 2*16*1024)
  int l  = idx >> 14;
  int bb = (idx >> 10) & 15;
  int hh = idx & 1023;
  int b = l * 8 + (bb >> 1);                          // torch flat-reshape mapping
  int j = ((bb & 1) << 10) | hh;
  float s = bvec[j];
  for (int k = 0; k < LAT; ++k) s += z[b * LAT + k] * w[k * (HID * 2) + j];
  h0[idx] = f2b(s);
}

// ---------------- embedding gather -> bf16 ----------------
__global__ __launch_bounds__(256) void k_embed(const float* __restrict__ emb, const int* __restrict__ inp,
                                               unsigned short* __restrict__ x) {
  int row = blockIdx.x;                               // B*S
  int tok = inp[row];
  for (int j = threadIdx.x; j < EMB; j += 256)
    x[(long)row * EMB + j] = f2b(emb[(long)tok * EMB + j]);
}

// ---------------- pred_w [K][N] fp32 -> [N][K] bf16 (tiled transpose) ----------------
__global__ void k_transpose(const float* __restrict__ src, unsigned short* __restrict__ dst) {
  __shared__ float tile[32][33];
  int n0 = blockIdx.x * 32;
  int k0 = blockIdx.y * 32;
  int tx = threadIdx.x, ty = threadIdx.y;
  for (int i = ty; i < 32; i += 8)
    tile[i][tx] = src[(long)(k0 + i) * VOCAB + n0 + tx];
  __syncthreads();
  for (int i = ty; i < 32; i += 8)
    dst[(long)(n0 + i) * HID + k0 + tx] = f2b(tile[tx][i]);
}

// ---------------- C[M][N] = A[M][K] * B[N][K]^T + bias[N]  (bf16 in, fp32 out) ----------------
// 128x128 tile, BK=64, 4 waves (2x2), each wave 4x4 frags of 16x16x32.
__global__ __launch_bounds__(256) void gemm_bt(const unsigned short* __restrict__ A,
                                               const unsigned short* __restrict__ Bm,
                                               const float* __restrict__ bias,
                                               float* __restrict__ C,
                                               int M, int N, int K) {
  const int LDT = 72;                                  // padded LDS K-stride (2-way conflicts only)
  extern __shared__ unsigned short smem_g[];
  unsigned short* As = smem_g;
  unsigned short* Bs = smem_g + 128 * LDT;

  int nTn = N >> 7;
  int tm = blockIdx.x / nTn, tn = blockIdx.x % nTn;
  long m0 = (long)tm << 7, n0 = (long)tn << 7;
  int t = threadIdx.x;
  int lane = t & 63, w = t >> 6;
  int wr = (w >> 1) * 64, wc = (w & 1) * 64;
  int fr = lane & 15, fg = lane >> 4;

  f32x4v acc[4][4];
  f32x4v zero = {0.f, 0.f, 0.f, 0.f};
#pragma unroll
  for (int i = 0; i < 4; ++i)
#pragma unroll
    for (int j = 0; j < 4; ++j) acc[i][j] = zero;

  int srow = t >> 3;
  int scol = (t & 7) << 3;

  for (int kt = 0; kt < K; kt += 64) {
#pragma unroll
    for (int it = 0; it < 4; ++it) {
      int row = srow + it * 32;
      bf16x8v va = *(const bf16x8v*)&A[(m0 + row) * K + kt + scol];
      bf16x8v vb = *(const bf16x8v*)&Bm[(n0 + row) * K + kt + scol];
      *(bf16x8v*)&As[row * LDT + scol] = va;
      *(bf16x8v*)&Bs[row * LDT + scol] = vb;
    }
    __syncthreads();
#pragma unroll
    for (int kk = 0; kk < 2; ++kk) {
      int ko = kk * 32 + fg * 8;
      bf16x8v af[4], bfv[4];
#pragma unroll
      for (int i = 0; i < 4; ++i) af[i] = *(const bf16x8v*)&As[(wr + i * 16 + fr) * LDT + ko];
#pragma unroll
      for (int j = 0; j < 4; ++j) bfv[j] = *(const bf16x8v*)&Bs[(wc + j * 16 + fr) * LDT + ko];
#pragma unroll
      for (int i = 0; i < 4; ++i)
#pragma unroll
        for (int j = 0; j < 4; ++j)
          acc[i][j] = __builtin_amdgcn_mfma_f32_16x16x32_bf16(af[i], bfv[j], acc[i][j], 0, 0, 0);
    }
    __syncthreads();
  }

#pragma unroll
  for (int j = 0; j < 4; ++j) {
    long n = n0 + wc + j * 16 + fr;
    float bv = bias[n];
#pragma unroll
    for (int i = 0; i < 4; ++i) {
      long mrow = m0 + wr + i * 16 + fg * 4;
#pragma unroll
      for (int r = 0; r < 4; ++r)
        C[(mrow + r) * (long)N + n] = acc[i][j][r] + bv;
    }
  }
}

// ---------------- persistent RNN scan: h = tanh(xw[t] + h @ Whh^T) ----------------
// 32 WGs x 1 wave; WG g owns output rows [g*32, g*32+32). Spin barrier each step.
__global__ __launch_bounds__(64) void k_scan(const unsigned short* __restrict__ Whh,
                                             const float* __restrict__ xw,
                                             const unsigned short* __restrict__ h0,
                                             unsigned short* __restrict__ ys,
                                             unsigned short* __restrict__ hping,
                                             unsigned int* __restrict__ cnt) {
  const int LDW = 1032;                                // padded: 2-way bank alias only
  extern __shared__ unsigned short Ws[];
  int lane = threadIdx.x;
  int nbase = blockIdx.x * 32;

  for (int c = lane; c < 32 * 128; c += 64) {          // stage 32 W rows (bf16) to LDS
    int row = c >> 7;
    int col = (c & 127) << 3;
    *(bf16x8v*)&Ws[row * LDW + col] = *(const bf16x8v*)&Whh[(long)(nbase + row) * HID + col];
  }
  __syncthreads();

  int fr = lane & 15, fg = lane >> 4;
  const unsigned short* hprev = h0;
  for (int t = 0; t < SS; ++t) {
    f32x4v acc0 = {0.f, 0.f, 0.f, 0.f};
    f32x4v acc1 = {0.f, 0.f, 0.f, 0.f};
#pragma unroll 8
    for (int kk = 0; kk < 32; ++kk) {
      int ko = kk * 32 + fg * 8;
      bf16x8v a  = *(const bf16x8v*)&hprev[fr * HID + ko];
      bf16x8v b0 = *(const bf16x8v*)&Ws[fr * LDW + ko];
      bf16x8v b1 = *(const bf16x8v*)&Ws[(16 + fr) * LDW + ko];
      acc0 = __builtin_amdgcn_mfma_f32_16x16x32_bf16(a, b0, acc0, 0, 0, 0);
      acc1 = __builtin_amdgcn_mfma_f32_16x16x32_bf16(a, b1, acc1, 0, 0, 0);
    }
    unsigned short* hnext = hping + ((t + 1) & 1) * (BB * HID);
#pragma unroll
    for (int r = 0; r < 4; ++r) {
      int b = fg * 4 + r;
      {
        int h = nbase + fr;
        float pre = acc0[r] + xw[((long)b * SS + t) * HID + h];
        unsigned short hb = f2b(tanhf(pre));
        ys[((long)b * SS + t) * HID + h] = hb;
        hnext[b * HID + h] = hb;
      }
      {
        int h = nbase + 16 + fr;
        float pre = acc1[r] + xw[((long)b * SS + t) * HID + h];
        unsigned short hb = f2b(tanhf(pre));
        ys[((long)b * SS + t) * HID + h] = hb;
        hnext[b * HID + h] = hb;
      }
    }
    if (lane == 0) {
      __hip_atomic_fetch_add(cnt, 1u, __ATOMIC_RELEASE, __HIP_MEMORY_SCOPE_AGENT);
      unsigned int target = 32u * (unsigned)(t + 1);
      while (__hip_atomic_load(cnt, __ATOMIC_ACQUIRE, __HIP_MEMORY_SCOPE_AGENT) < target)
        __builtin_amdgcn_s_sleep(1);
    }
    __syncthreads();
    hprev = hping + ((t + 1) & 1) * (BB * HID);
  }
}

extern "C" void kernel_launch(void* const* d_in, const int* in_sizes, int n_in,
                              void* d_out, int out_size, void* d_ws, size_t ws_size,
                              hipStream_t stream) {
  const float* z     = (const float*)d_in[0];
  const int*   inp   = (const int*)d_in[1];
  const float* emb   = (const float*)d_in[2];
  const float* l2h_w = (const float*)d_in[3];
  const float* l2h_b = (const float*)d_in[4];
  const float* wih0  = (const float*)d_in[5];
  const float* whh0  = (const float*)d_in[6];
  const float* bih0  = (const float*)d_in[7];
  const float* bhh0  = (const float*)d_in[8];
  const float* wih1  = (const float*)d_in[9];
  const float* whh1  = (const float*)d_in[10];
  const float* bih1  = (const float*)d_in[11];
  const float* bhh1  = (const float*)d_in[12];
  const float* predw = (const float*)d_in[13];
  const float* predb = (const float*)d_in[14];
  float* out = (float*)d_out;

  char* ws = (char*)d_ws;
  size_t off = 0;
  auto alloc = [&](size_t bytes) {
    char* p = ws + off;
    off = (off + bytes + 255) & ~(size_t)255;
    return p;
  };
  unsigned short* xb     = (unsigned short*)alloc((size_t)BB * SS * EMB * 2);
  unsigned short* wih0b  = (unsigned short*)alloc((size_t)HID * EMB * 2);
  unsigned short* whh0b  = (unsigned short*)alloc((size_t)HID * HID * 2);
  unsigned short* wih1b  = (unsigned short*)alloc((size_t)HID * HID * 2);
  unsigned short* whh1b  = (unsigned short*)alloc((size_t)HID * HID * 2);
  unsigned short* predTb = (unsigned short*)alloc((size_t)VOCAB * HID * 2);
  float*          xw0    = (float*)alloc((size_t)BB * SS * HID * 4);
  float*          xw1    = (float*)alloc((size_t)BB * SS * HID * 4);
  unsigned short* ys0    = (unsigned short*)alloc((size_t)BB * SS * HID * 2);
  unsigned short* ys1    = (unsigned short*)alloc((size_t)BB * SS * HID * 2);
  unsigned short* h0b    = (unsigned short*)alloc((size_t)2 * BB * HID * 2);
  unsigned short* hping  = (unsigned short*)alloc((size_t)2 * BB * HID * 2);
  float*          bias0  = (float*)alloc((size_t)HID * 4);
  float*          bias1  = (float*)alloc((size_t)HID * 4);
  unsigned int*   cnt    = (unsigned int*)alloc(256);

  // prep
  k_f2b<<<256, 256, 0, stream>>>(wih0, wih0b, HID * EMB);
  k_f2b<<<256, 256, 0, stream>>>(whh0, whh0b, HID * HID);
  k_f2b<<<256, 256, 0, stream>>>(wih1, wih1b, HID * HID);
  k_f2b<<<256, 256, 0, stream>>>(whh1, whh1b, HID * HID);
  k_misc<<<4, 256, 0, stream>>>(bih0, bhh0, bih1, bhh1, bias0, bias1, cnt);
  k_latent<<<(2 * BB * HID) / 256, 256, 0, stream>>>(z, l2h_w, l2h_b, h0b);
  k_embed<<<BB * SS, 256, 0, stream>>>(emb, inp, xb);
  k_transpose<<<dim3(VOCAB / 32, HID / 32), dim3(32, 8), 0, stream>>>(predw, predTb);

  size_t gemm_lds = (size_t)2 * 128 * 72 * 2;
  size_t scan_lds = (size_t)32 * 1032 * 2;

  // xw0 = x @ w_ih0^T + (b_ih0 + b_hh0)
  gemm_bt<<<(BB * SS / 128) * (HID / 128), 256, gemm_lds, stream>>>(xb, wih0b, bias0, xw0, BB * SS, HID, EMB);
  // layer 0 scan
  k_scan<<<32, 64, scan_lds, stream>>>(whh0b, xw0, h0b, ys0, hping, cnt + 0);
  // xw1 = h1 @ w_ih1^T + (b_ih1 + b_hh1)
  gemm_bt<<<(BB * SS / 128) * (HID / 128), 256, gemm_lds, stream>>>(ys0, wih1b, bias1, xw1, BB * SS, HID, HID);
  // layer 1 scan
  k_scan<<<32, 64, scan_lds, stream>>>(whh1b, xw1, h0b + BB * HID, ys1, hping, cnt + 1);
  // logits = h2 @ pred_w + pred_b
  gemm_bt<<<(BB * SS / 128) * (VOCAB / 128), 256, gemm_lds, stream>>>(ys1, predTb, predb, out, BB * SS, VOCAB, HID);
}

// Round 2
// 8999.964 us; speedup vs baseline: 1.1730x; 1.1730x over previous
//
#include <hip/hip_runtime.h>
#include <hip/hip_bf16.h>

#define BB 16
#define SS 512
#define VOCAB 32000
#define EMB 512
#define HID 1024
#define LAT 256

typedef __attribute__((ext_vector_type(8))) short bf16x8v;
typedef __attribute__((ext_vector_type(4))) float f32x4v;

__device__ __forceinline__ unsigned short f2b(float f) {
  unsigned int u = __float_as_uint(f);
  unsigned int r = (u + 0x7fffu + ((u >> 16) & 1u)) >> 16;
  return (unsigned short)r;
}

__device__ __forceinline__ float b2f(unsigned short s) {
  return __uint_as_float(((unsigned int)s) << 16);
}

__device__ __forceinline__ float fast_tanh(float x) {
  // tanh(x) = (e-1)/(e+1), e = 2^(x*2*log2(e)); clamp keeps exp2 finite.
  float t = fminf(fmaxf(x * 2.8853900817779268f, -60.f), 60.f);
  float e = __builtin_amdgcn_exp2f(t);
  return (e - 1.f) * __builtin_amdgcn_rcpf(e + 1.f);
}

// ---------------- generic fp32 -> bf16 ----------------
__global__ __launch_bounds__(256) void k_f2b(const float* __restrict__ src,
                                             unsigned short* __restrict__ dst, int n) {
  int i = blockIdx.x * 256 + threadIdx.x;
  int stride = gridDim.x * 256;
  for (; i < n; i += stride) dst[i] = f2b(src[i]);
}

// ---------------- biases + flag zeroing ----------------
__global__ __launch_bounds__(256) void k_misc(const float* __restrict__ bih0, const float* __restrict__ bhh0,
                                              const float* __restrict__ bih1, const float* __restrict__ bhh1,
                                              float* __restrict__ bias0, float* __restrict__ bias1,
                                              unsigned int* __restrict__ flags, int nflags) {
  int i = blockIdx.x * 256 + threadIdx.x;
  if (i < HID) { bias0[i] = bih0[i] + bhh0[i]; bias1[i] = bih1[i] + bhh1[i]; }
  if (i < nflags) flags[i] = 0u;
}

// ---------------- hidden = z @ l2h_w + b, torch-reshape to [2][16][1024], bf16 ----------------
__global__ __launch_bounds__(256) void k_latent(const float* __restrict__ z, const float* __restrict__ w,
                                                const float* __restrict__ bvec, unsigned short* __restrict__ h0) {
  int idx = blockIdx.x * 256 + threadIdx.x;          // [0, 2*16*1024)
  int l  = idx >> 14;
  int bb = (idx >> 10) & 15;
  int hh = idx & 1023;
  int b = l * 8 + (bb >> 1);                          // torch flat-reshape mapping
  int j = ((bb & 1) << 10) | hh;
  float s = bvec[j];
  for (int k = 0; k < LAT; ++k) s += z[b * LAT + k] * w[k * (HID * 2) + j];
  h0[idx] = f2b(s);
}

// ---------------- embedding gather -> bf16 ----------------
__global__ __launch_bounds__(256) void k_embed(const float* __restrict__ emb, const int* __restrict__ inp,
                                               unsigned short* __restrict__ x) {
  int row = blockIdx.x;                               // B*S
  int tok = inp[row];
  for (int j = threadIdx.x; j < EMB; j += 256)
    x[(long)row * EMB + j] = f2b(emb[(long)tok * EMB + j]);
}

// ---------------- pred_w [K][N] fp32 -> [N][K] bf16 (tiled transpose) ----------------
__global__ void k_transpose(const float* __restrict__ src, unsigned short* __restrict__ dst) {
  __shared__ float tile[32][33];
  int n0 = blockIdx.x * 32;
  int k0 = blockIdx.y * 32;
  int tx = threadIdx.x, ty = threadIdx.y;
  for (int i = ty; i < 32; i += 8)
    tile[i][tx] = src[(long)(k0 + i) * VOCAB + n0 + tx];
  __syncthreads();
  for (int i = ty; i < 32; i += 8)
    dst[(long)(n0 + i) * HID + k0 + tx] = f2b(tile[tx][i]);
}

// ---------------- C[M][N] = A[M][K] * B[N][K]^T + bias[N]  (bf16 in, OUT out) ----------------
template <typename OUT>
__global__ __launch_bounds__(256) void gemm_bt(const unsigned short* __restrict__ A,
                                               const unsigned short* __restrict__ Bm,
                                               const float* __restrict__ bias,
                                               OUT* __restrict__ C,
                                               int M, int N, int K) {
  const int LDT = 72;                                  // padded LDS K-stride
  extern __shared__ unsigned short smem_g[];
  unsigned short* As = smem_g;
  unsigned short* Bs = smem_g + 128 * LDT;

  int nTn = N >> 7;
  int tm = blockIdx.x / nTn, tn = blockIdx.x % nTn;
  long m0 = (long)tm << 7, n0 = (long)tn << 7;
  int t = threadIdx.x;
  int lane = t & 63, w = t >> 6;
  int wr = (w >> 1) * 64, wc = (w & 1) * 64;
  int fr = lane & 15, fg = lane >> 4;

  f32x4v acc[4][4];
  f32x4v zero = {0.f, 0.f, 0.f, 0.f};
#pragma unroll
  for (int i = 0; i < 4; ++i)
#pragma unroll
    for (int j = 0; j < 4; ++j) acc[i][j] = zero;

  int srow = t >> 3;
  int scol = (t & 7) << 3;

  for (int kt = 0; kt < K; kt += 64) {
#pragma unroll
    for (int it = 0; it < 4; ++it) {
      int row = srow + it * 32;
      bf16x8v va = *(const bf16x8v*)&A[(m0 + row) * K + kt + scol];
      bf16x8v vb = *(const bf16x8v*)&Bm[(n0 + row) * K + kt + scol];
      *(bf16x8v*)&As[row * LDT + scol] = va;
      *(bf16x8v*)&Bs[row * LDT + scol] = vb;
    }
    __syncthreads();
#pragma unroll
    for (int kk = 0; kk < 2; ++kk) {
      int ko = kk * 32 + fg * 8;
      bf16x8v af[4], bfv[4];
#pragma unroll
      for (int i = 0; i < 4; ++i) af[i] = *(const bf16x8v*)&As[(wr + i * 16 + fr) * LDT + ko];
#pragma unroll
      for (int j = 0; j < 4; ++j) bfv[j] = *(const bf16x8v*)&Bs[(wc + j * 16 + fr) * LDT + ko];
#pragma unroll
      for (int i = 0; i < 4; ++i)
#pragma unroll
        for (int j = 0; j < 4; ++j)
          acc[i][j] = __builtin_amdgcn_mfma_f32_16x16x32_bf16(af[i], bfv[j], acc[i][j], 0, 0, 0);
    }
    __syncthreads();
  }

#pragma unroll
  for (int j = 0; j < 4; ++j) {
    long n = n0 + wc + j * 16 + fr;
    float bv = bias[n];
#pragma unroll
    for (int i = 0; i < 4; ++i) {
      long mrow = m0 + wr + i * 16 + fg * 4;
#pragma unroll
      for (int r = 0; r < 4; ++r) {
        float v = acc[i][j][r] + bv;
        if constexpr (__hip_internal::is_same<OUT, float>::value) {
          C[(mrow + r) * (long)N + n] = v;
        } else {
          C[(mrow + r) * (long)N + n] = f2b(v);
        }
      }
    }
  }
}

// ---------------- persistent RNN scan: h = tanh(xw[t] + h @ Whh^T) ----------------
// 32 WGs x 1 wave; WG g owns output cols [g*32, g*32+32).
// Barrier v2: per-WG flag lines + write-through (agent-relaxed atomic) h stores.
__global__ __launch_bounds__(64) void k_scan(const unsigned short* __restrict__ Whh,
                                             const unsigned short* __restrict__ xw,   // [B][S][H] bf16
                                             const unsigned short* __restrict__ h0,   // [B][H] bf16
                                             unsigned short* __restrict__ ys,         // [B][S][H] bf16
                                             unsigned short* __restrict__ hping,      // 2 x [B][H] bf16
                                             unsigned int* __restrict__ flags) {      // 32 x 16 uints
  const int LDW = 1032;                                // padded: 2-way bank alias only
  extern __shared__ unsigned short Ws[];
  int lane = threadIdx.x;
  int wg = blockIdx.x;
  int nbase = wg * 32;

  for (int c = lane; c < 32 * 128; c += 64) {          // stage 32 W rows (bf16) to LDS
    int row = c >> 7;
    int col = (c & 127) << 3;
    *(bf16x8v*)&Ws[row * LDW + col] = *(const bf16x8v*)&Whh[(long)(nbase + row) * HID + col];
  }
  __syncthreads();

  int fr = lane & 15, fg = lane >> 4;
  int odd = fr & 1;
  int scol = odd ? (nbase + 16 + fr - 1) : (nbase + fr);  // packed-pair store column (even)

  for (int t = 0; t < SS; ++t) {
    // ---- prefetch xw[t] (independent of h) before the barrier wait ----
    unsigned short xv0[4], xv1[4];
#pragma unroll
    for (int r = 0; r < 4; ++r) {
      int b = fg * 4 + r;
      xv0[r] = xw[((long)b * SS + t) * HID + nbase + fr];
      xv1[r] = xw[((long)b * SS + t) * HID + nbase + 16 + fr];
    }

    // ---- step barrier: wait for all WGs to have finished step t-1 ----
    if (t > 0) {
      unsigned tgt = (unsigned)t;
      for (;;) {
        unsigned v = 0xffffffffu;
        if (lane < 32)
          v = __hip_atomic_load(&flags[lane << 4], __ATOMIC_ACQUIRE, __HIP_MEMORY_SCOPE_AGENT);
        if (__all(v >= tgt)) break;
      }
      __builtin_amdgcn_fence(__ATOMIC_ACQUIRE, "agent");
    }
    const unsigned short* hprev = (t == 0) ? h0 : (hping + (t & 1) * (BB * HID));

    // ---- issue all h loads up front ----
    bf16x8v hf[32];
#pragma unroll
    for (int kk = 0; kk < 32; ++kk) {
      int ko = kk * 32 + fg * 8;
      hf[kk] = *(const bf16x8v*)&hprev[fr * HID + ko];
    }

    f32x4v acc0 = {0.f, 0.f, 0.f, 0.f};
    f32x4v acc1 = {0.f, 0.f, 0.f, 0.f};
#pragma unroll
    for (int kk = 0; kk < 32; ++kk) {
      int ko = kk * 32 + fg * 8;
      bf16x8v b0 = *(const bf16x8v*)&Ws[fr * LDW + ko];
      bf16x8v b1 = *(const bf16x8v*)&Ws[(16 + fr) * LDW + ko];
      acc0 = __builtin_amdgcn_mfma_f32_16x16x32_bf16(hf[kk], b0, acc0, 0, 0, 0);
      acc1 = __builtin_amdgcn_mfma_f32_16x16x32_bf16(hf[kk], b1, acc1, 0, 0, 0);
    }

    unsigned short* hnext = hping + ((t + 1) & 1) * (BB * HID);
#pragma unroll
    for (int r = 0; r < 4; ++r) {
      int b = fg * 4 + r;
      unsigned int a0 = (unsigned int)f2b(fast_tanh(acc0[r] + b2f(xv0[r])));   // col nbase+fr
      unsigned int a1 = (unsigned int)f2b(fast_tanh(acc1[r] + b2f(xv1[r])));   // col nbase+16+fr
      unsigned int p0 = __shfl_xor(a0, 1);
      unsigned int p1 = __shfl_xor(a1, 1);
      // even lane: pack chain0 pair (fr, fr+1); odd lane: pack chain1 pair (16+fr-1, 16+fr)
      unsigned int val = odd ? (p1 | (a1 << 16)) : (a0 | (p0 << 16));
      long base = (long)b * HID + scol;
      *(unsigned int*)&ys[((long)b * SS + t) * HID + scol] = val;               // plain store
      __hip_atomic_store((unsigned int*)&hnext[base], val,
                         __ATOMIC_RELAXED, __HIP_MEMORY_SCOPE_AGENT);           // write-through
    }

    __syncthreads();   // drains vmcnt on the wave: h stores are at coherence point
    if (lane == 0)
      __hip_atomic_store(&flags[wg << 4], (unsigned)(t + 1),
                         __ATOMIC_RELEASE, __HIP_MEMORY_SCOPE_AGENT);
  }
}

extern "C" void kernel_launch(void* const* d_in, const int* in_sizes, int n_in,
                              void* d_out, int out_size, void* d_ws, size_t ws_size,
                              hipStream_t stream) {
  const float* z     = (const float*)d_in[0];
  const int*   inp   = (const int*)d_in[1];
  const float* emb   = (const float*)d_in[2];
  const float* l2h_w = (const float*)d_in[3];
  const float* l2h_b = (const float*)d_in[4];
  const float* wih0  = (const float*)d_in[5];
  const float* whh0  = (const float*)d_in[6];
  const float* bih0  = (const float*)d_in[7];
  const float* bhh0  = (const float*)d_in[8];
  const float* wih1  = (const float*)d_in[9];
  const float* whh1  = (const float*)d_in[10];
  const float* bih1  = (const float*)d_in[11];
  const float* bhh1  = (const float*)d_in[12];
  const float* predw = (const float*)d_in[13];
  const float* predb = (const float*)d_in[14];
  float* out = (float*)d_out;

  char* ws = (char*)d_ws;
  size_t off = 0;
  auto alloc = [&](size_t bytes) {
    char* p = ws + off;
    off = (off + bytes + 255) & ~(size_t)255;
    return p;
  };
  unsigned short* xb     = (unsigned short*)alloc((size_t)BB * SS * EMB * 2);
  unsigned short* wih0b  = (unsigned short*)alloc((size_t)HID * EMB * 2);
  unsigned short* whh0b  = (unsigned short*)alloc((size_t)HID * HID * 2);
  unsigned short* wih1b  = (unsigned short*)alloc((size_t)HID * HID * 2);
  unsigned short* whh1b  = (unsigned short*)alloc((size_t)HID * HID * 2);
  unsigned short* predTb = (unsigned short*)alloc((size_t)VOCAB * HID * 2);
  unsigned short* xw0    = (unsigned short*)alloc((size_t)BB * SS * HID * 2);
  unsigned short* xw1    = (unsigned short*)alloc((size_t)BB * SS * HID * 2);
  unsigned short* ys0    = (unsigned short*)alloc((size_t)BB * SS * HID * 2);
  unsigned short* ys1    = (unsigned short*)alloc((size_t)BB * SS * HID * 2);
  unsigned short* h0b    = (unsigned short*)alloc((size_t)2 * BB * HID * 2);
  unsigned short* hping  = (unsigned short*)alloc((size_t)2 * BB * HID * 2);
  float*          bias0  = (float*)alloc((size_t)HID * 4);
  float*          bias1  = (float*)alloc((size_t)HID * 4);
  unsigned int*   flags  = (unsigned int*)alloc((size_t)1024 * 4);  // 2 layers x 32 WGs x 16

  // prep
  k_f2b<<<256, 256, 0, stream>>>(wih0, wih0b, HID * EMB);
  k_f2b<<<256, 256, 0, stream>>>(whh0, whh0b, HID * HID);
  k_f2b<<<256, 256, 0, stream>>>(wih1, wih1b, HID * HID);
  k_f2b<<<256, 256, 0, stream>>>(whh1, whh1b, HID * HID);
  k_misc<<<4, 256, 0, stream>>>(bih0, bhh0, bih1, bhh1, bias0, bias1, flags, 1024);
  k_latent<<<(2 * BB * HID) / 256, 256, 0, stream>>>(z, l2h_w, l2h_b, h0b);
  k_embed<<<BB * SS, 256, 0, stream>>>(emb, inp, xb);
  k_transpose<<<dim3(VOCAB / 32, HID / 32), dim3(32, 8), 0, stream>>>(predw, predTb);

  size_t gemm_lds = (size_t)2 * 128 * 72 * 2;
  size_t scan_lds = (size_t)32 * 1032 * 2;

  // xw0 = x @ w_ih0^T + (b_ih0 + b_hh0)   -> bf16
  gemm_bt<unsigned short><<<(BB * SS / 128) * (HID / 128), 256, gemm_lds, stream>>>(
      xb, wih0b, bias0, xw0, BB * SS, HID, EMB);
  // layer 0 scan
  k_scan<<<32, 64, scan_lds, stream>>>(whh0b, xw0, h0b, ys0, hping, flags);
  // xw1 = h1 @ w_ih1^T + (b_ih1 + b_hh1)  -> bf16
  gemm_bt<unsigned short><<<(BB * SS / 128) * (HID / 128), 256, gemm_lds, stream>>>(
      ys0, wih1b, bias1, xw1, BB * SS, HID, HID);
  // layer 1 scan
  k_scan<<<32, 64, scan_lds, stream>>>(whh1b, xw1, h0b + BB * HID, ys1, hping, flags + 512);
  // logits = h2 @ pred_w + pred_b  -> fp32 (d_out)
  gemm_bt<float><<<(BB * SS / 128) * (VOCAB / 128), 256, gemm_lds, stream>>>(
      ys1, predTb, predb, out, BB * SS, VOCAB, HID);
}

// Round 3
// 5065.060 us; speedup vs baseline: 2.0844x; 1.7769x over previous
//
#include <hip/hip_runtime.h>
#include <hip/hip_bf16.h>

#define BB 16
#define SS 512
#define VOCAB 32000
#define EMB 512
#define HID 1024
#define LAT 256

typedef __attribute__((ext_vector_type(8))) short bf16x8v;
typedef __attribute__((ext_vector_type(4))) float f32x4v;

__device__ __forceinline__ unsigned short f2b(float f) {
  unsigned int u = __float_as_uint(f);
  unsigned int r = (u + 0x7fffu + ((u >> 16) & 1u)) >> 16;
  return (unsigned short)r;
}

__device__ __forceinline__ float b2f(unsigned short s) {
  return __uint_as_float(((unsigned int)s) << 16);
}

__device__ __forceinline__ float fast_tanh(float x) {
  float t = fminf(fmaxf(x * 2.8853900817779268f, -60.f), 60.f);
  float e = __builtin_amdgcn_exp2f(t);
  return (e - 1.f) * __builtin_amdgcn_rcpf(e + 1.f);
}

// coherent-point 16B load: bypass (possibly stale) L1/L2, read LLC directly.
__device__ __forceinline__ bf16x8v load16_coherent(const unsigned short* p) {
  bf16x8v r;
  asm volatile("global_load_dwordx4 %0, %1, off sc0 sc1"
               : "=v"(r) : "v"(p) : "memory");
  return r;
}

// ---------------- generic fp32 -> bf16 ----------------
__global__ __launch_bounds__(256) void k_f2b(const float* __restrict__ src,
                                             unsigned short* __restrict__ dst, int n) {
  int i = blockIdx.x * 256 + threadIdx.x;
  int stride = gridDim.x * 256;
  for (; i < n; i += stride) dst[i] = f2b(src[i]);
}

// ---------------- biases + flag zeroing ----------------
__global__ __launch_bounds__(256) void k_misc(const float* __restrict__ bih0, const float* __restrict__ bhh0,
                                              const float* __restrict__ bih1, const float* __restrict__ bhh1,
                                              float* __restrict__ bias0, float* __restrict__ bias1,
                                              unsigned int* __restrict__ flags, int nflags) {
  int i = blockIdx.x * 256 + threadIdx.x;
  if (i < HID) { bias0[i] = bih0[i] + bhh0[i]; bias1[i] = bih1[i] + bhh1[i]; }
  if (i < nflags) flags[i] = 0u;
}

// ---------------- hidden = z @ l2h_w + b, torch-reshape to [2][16][1024], bf16 ----------------
__global__ __launch_bounds__(256) void k_latent(const float* __restrict__ z, const float* __restrict__ w,
                                                const float* __restrict__ bvec, unsigned short* __restrict__ h0) {
  int idx = blockIdx.x * 256 + threadIdx.x;          // [0, 2*16*1024)
  int l  = idx >> 14;
  int bb = (idx >> 10) & 15;
  int hh = idx & 1023;
  int b = l * 8 + (bb >> 1);                          // torch flat-reshape mapping
  int j = ((bb & 1) << 10) | hh;
  float s = bvec[j];
  for (int k = 0; k < LAT; ++k) s += z[b * LAT + k] * w[k * (HID * 2) + j];
  h0[idx] = f2b(s);
}

// ---------------- embedding gather -> bf16 ----------------
__global__ __launch_bounds__(256) void k_embed(const float* __restrict__ emb, const int* __restrict__ inp,
                                               unsigned short* __restrict__ x) {
  int row = blockIdx.x;                               // B*S
  int tok = inp[row];
  for (int j = threadIdx.x; j < EMB; j += 256)
    x[(long)row * EMB + j] = f2b(emb[(long)tok * EMB + j]);
}

// ---------------- pred_w [K][N] fp32 -> [N][K] bf16 (tiled transpose) ----------------
__global__ void k_transpose(const float* __restrict__ src, unsigned short* __restrict__ dst) {
  __shared__ float tile[32][33];
  int n0 = blockIdx.x * 32;
  int k0 = blockIdx.y * 32;
  int tx = threadIdx.x, ty = threadIdx.y;
  for (int i = ty; i < 32; i += 8)
    tile[i][tx] = src[(long)(k0 + i) * VOCAB + n0 + tx];
  __syncthreads();
  for (int i = ty; i < 32; i += 8)
    dst[(long)(n0 + i) * HID + k0 + tx] = f2b(tile[tx][i]);
}

// ---------------- C[M][N] = A[M][K] * B[N][K]^T + bias[N]  (bf16 in, OUT out) ----------------
template <typename OUT>
__global__ __launch_bounds__(256) void gemm_bt(const unsigned short* __restrict__ A,
                                               const unsigned short* __restrict__ Bm,
                                               const float* __restrict__ bias,
                                               OUT* __restrict__ C,
                                               int M, int N, int K) {
  const int LDT = 72;                                  // padded LDS K-stride
  extern __shared__ unsigned short smem_g[];
  unsigned short* As = smem_g;
  unsigned short* Bs = smem_g + 128 * LDT;

  int nTn = N >> 7;
  int tm = blockIdx.x / nTn, tn = blockIdx.x % nTn;
  long m0 = (long)tm << 7, n0 = (long)tn << 7;
  int t = threadIdx.x;
  int lane = t & 63, w = t >> 6;
  int wr = (w >> 1) * 64, wc = (w & 1) * 64;
  int fr = lane & 15, fg = lane >> 4;

  f32x4v acc[4][4];
  f32x4v zero = {0.f, 0.f, 0.f, 0.f};
#pragma unroll
  for (int i = 0; i < 4; ++i)
#pragma unroll
    for (int j = 0; j < 4; ++j) acc[i][j] = zero;

  int srow = t >> 3;
  int scol = (t & 7) << 3;

  for (int kt = 0; kt < K; kt += 64) {
#pragma unroll
    for (int it = 0; it < 4; ++it) {
      int row = srow + it * 32;
      bf16x8v va = *(const bf16x8v*)&A[(m0 + row) * K + kt + scol];
      bf16x8v vb = *(const bf16x8v*)&Bm[(n0 + row) * K + kt + scol];
      *(bf16x8v*)&As[row * LDT + scol] = va;
      *(bf16x8v*)&Bs[row * LDT + scol] = vb;
    }
    __syncthreads();
#pragma unroll
    for (int kk = 0; kk < 2; ++kk) {
      int ko = kk * 32 + fg * 8;
      bf16x8v af[4], bfv[4];
#pragma unroll
      for (int i = 0; i < 4; ++i) af[i] = *(const bf16x8v*)&As[(wr + i * 16 + fr) * LDT + ko];
#pragma unroll
      for (int j = 0; j < 4; ++j) bfv[j] = *(const bf16x8v*)&Bs[(wc + j * 16 + fr) * LDT + ko];
#pragma unroll
      for (int i = 0; i < 4; ++i)
#pragma unroll
        for (int j = 0; j < 4; ++j)
          acc[i][j] = __builtin_amdgcn_mfma_f32_16x16x32_bf16(af[i], bfv[j], acc[i][j], 0, 0, 0);
    }
    __syncthreads();
  }

#pragma unroll
  for (int j = 0; j < 4; ++j) {
    long n = n0 + wc + j * 16 + fr;
    float bv = bias[n];
#pragma unroll
    for (int i = 0; i < 4; ++i) {
      long mrow = m0 + wr + i * 16 + fg * 4;
#pragma unroll
      for (int r = 0; r < 4; ++r) {
        float v = acc[i][j][r] + bv;
        if constexpr (__hip_internal::is_same<OUT, float>::value) {
          C[(mrow + r) * (long)N + n] = v;
        } else {
          C[(mrow + r) * (long)N + n] = f2b(v);
        }
      }
    }
  }
}

// ---------------- persistent RNN scan: h = tanh(xw[t] + h @ Whh^T) ----------------
// 32 WGs x 1 wave; WG g owns output cols [g*32, g*32+32).
// Barrier v3: zero cache-maintenance. Relaxed polls; coherent (sc0 sc1) h loads;
// hand-rolled release (vmcnt ack -> relaxed flag store).
__global__ __launch_bounds__(64, 1) void k_scan(const unsigned short* __restrict__ Whh,
                                                const unsigned short* __restrict__ xw,   // [B][S][H] bf16
                                                const unsigned short* __restrict__ h0,   // [B][H] bf16
                                                unsigned short* __restrict__ ys,         // [B][S][H] bf16
                                                unsigned short* __restrict__ hping,      // 2 x [B][H] bf16
                                                unsigned int* __restrict__ flags) {      // 32 x 16 uints
  const int LDW = 1032;                                // padded: 2-way bank alias only
  extern __shared__ unsigned short Ws[];
  int lane = threadIdx.x;
  int wg = blockIdx.x;
  int nbase = wg * 32;

  for (int c = lane; c < 32 * 128; c += 64) {          // stage 32 W rows (bf16) to LDS
    int row = c >> 7;
    int col = (c & 127) << 3;
    *(bf16x8v*)&Ws[row * LDW + col] = *(const bf16x8v*)&Whh[(long)(nbase + row) * HID + col];
  }
  __syncthreads();

  int fr = lane & 15, fg = lane >> 4;
  int odd = fr & 1;
  int scol = odd ? (nbase + 16 + fr - 1) : (nbase + fr);  // packed-pair store column (even)

  for (int t = 0; t < SS; ++t) {
    // ---- prefetch xw[t] (independent of h) before the poll ----
    unsigned short xv0[4], xv1[4];
#pragma unroll
    for (int r = 0; r < 4; ++r) {
      int b = fg * 4 + r;
      xv0[r] = xw[((long)b * SS + t) * HID + nbase + fr];
      xv1[r] = xw[((long)b * SS + t) * HID + nbase + 16 + fr];
    }

    // ---- step barrier: relaxed polls only (no per-iter invalidates) ----
    if (t > 0) {
      unsigned tgt = (unsigned)t;
      for (;;) {
        unsigned v = 0xffffffffu;
        if (lane < 32)
          v = __hip_atomic_load(&flags[lane << 4], __ATOMIC_RELAXED, __HIP_MEMORY_SCOPE_AGENT);
        if (__all(v >= tgt)) break;
      }
    }
    const unsigned short* hprev = (t == 0) ? h0 : (hping + (t & 1) * (BB * HID));

    // ---- h loads: coherent-point reads, all issued up front ----
    bf16x8v hf[32];
#pragma unroll
    for (int kk = 0; kk < 32; ++kk) {
      int ko = kk * 32 + fg * 8;
      hf[kk] = load16_coherent(&hprev[fr * HID + ko]);
    }
    asm volatile("s_waitcnt vmcnt(0)" ::: "memory");
    __builtin_amdgcn_sched_barrier(0);

    f32x4v acc0 = {0.f, 0.f, 0.f, 0.f};
    f32x4v acc1 = {0.f, 0.f, 0.f, 0.f};
#pragma unroll
    for (int kk = 0; kk < 32; ++kk) {
      int ko = kk * 32 + fg * 8;
      bf16x8v b0 = *(const bf16x8v*)&Ws[fr * LDW + ko];
      bf16x8v b1 = *(const bf16x8v*)&Ws[(16 + fr) * LDW + ko];
      acc0 = __builtin_amdgcn_mfma_f32_16x16x32_bf16(hf[kk], b0, acc0, 0, 0, 0);
      acc1 = __builtin_amdgcn_mfma_f32_16x16x32_bf16(hf[kk], b1, acc1, 0, 0, 0);
    }

    unsigned short* hnext = hping + ((t + 1) & 1) * (BB * HID);
    unsigned int ysv[4];
#pragma unroll
    for (int r = 0; r < 4; ++r) {
      int b = fg * 4 + r;
      unsigned int a0 = (unsigned int)f2b(fast_tanh(acc0[r] + b2f(xv0[r])));   // col nbase+fr
      unsigned int a1 = (unsigned int)f2b(fast_tanh(acc1[r] + b2f(xv1[r])));   // col nbase+16+fr
      unsigned int p0 = __shfl_xor(a0, 1);
      unsigned int p1 = __shfl_xor(a1, 1);
      unsigned int val = odd ? (p1 | (a1 << 16)) : (a0 | (p0 << 16));
      ysv[r] = val;
      __hip_atomic_store((unsigned int*)&hnext[(long)b * HID + scol], val,
                         __ATOMIC_RELAXED, __HIP_MEMORY_SCOPE_AGENT);           // write-through
    }

    asm volatile("s_waitcnt vmcnt(0)" ::: "memory");    // h stores ack'd at coherence point
    if (lane == 0)
      __hip_atomic_store(&flags[wg << 4], (unsigned)(t + 1),
                         __ATOMIC_RELAXED, __HIP_MEMORY_SCOPE_AGENT);

    // ---- ys stores off the critical path ----
#pragma unroll
    for (int r = 0; r < 4; ++r) {
      int b = fg * 4 + r;
      *(unsigned int*)&ys[((long)b * SS + t) * HID + scol] = ysv[r];
    }
  }
}

extern "C" void kernel_launch(void* const* d_in, const int* in_sizes, int n_in,
                              void* d_out, int out_size, void* d_ws, size_t ws_size,
                              hipStream_t stream) {
  const float* z     = (const float*)d_in[0];
  const int*   inp   = (const int*)d_in[1];
  const float* emb   = (const float*)d_in[2];
  const float* l2h_w = (const float*)d_in[3];
  const float* l2h_b = (const float*)d_in[4];
  const float* wih0  = (const float*)d_in[5];
  const float* whh0  = (const float*)d_in[6];
  const float* bih0  = (const float*)d_in[7];
  const float* bhh0  = (const float*)d_in[8];
  const float* wih1  = (const float*)d_in[9];
  const float* whh1  = (const float*)d_in[10];
  const float* bih1  = (const float*)d_in[11];
  const float* bhh1  = (const float*)d_in[12];
  const float* predw = (const float*)d_in[13];
  const float* predb = (const float*)d_in[14];
  float* out = (float*)d_out;

  char* ws = (char*)d_ws;
  size_t off = 0;
  auto alloc = [&](size_t bytes) {
    char* p = ws + off;
    off = (off + bytes + 255) & ~(size_t)255;
    return p;
  };
  unsigned short* xb     = (unsigned short*)alloc((size_t)BB * SS * EMB * 2);
  unsigned short* wih0b  = (unsigned short*)alloc((size_t)HID * EMB * 2);
  unsigned short* whh0b  = (unsigned short*)alloc((size_t)HID * HID * 2);
  unsigned short* wih1b  = (unsigned short*)alloc((size_t)HID * HID * 2);
  unsigned short* whh1b  = (unsigned short*)alloc((size_t)HID * HID * 2);
  unsigned short* predTb = (unsigned short*)alloc((size_t)VOCAB * HID * 2);
  unsigned short* xw0    = (unsigned short*)alloc((size_t)BB * SS * HID * 2);
  unsigned short* xw1    = (unsigned short*)alloc((size_t)BB * SS * HID * 2);
  unsigned short* ys0    = (unsigned short*)alloc((size_t)BB * SS * HID * 2);
  unsigned short* ys1    = (unsigned short*)alloc((size_t)BB * SS * HID * 2);
  unsigned short* h0b    = (unsigned short*)alloc((size_t)2 * BB * HID * 2);
  unsigned short* hping  = (unsigned short*)alloc((size_t)2 * BB * HID * 2);
  float*          bias0  = (float*)alloc((size_t)HID * 4);
  float*          bias1  = (float*)alloc((size_t)HID * 4);
  unsigned int*   flags  = (unsigned int*)alloc((size_t)1024 * 4);  // 2 layers x 32 WGs x 16

  // prep
  k_f2b<<<256, 256, 0, stream>>>(wih0, wih0b, HID * EMB);
  k_f2b<<<256, 256, 0, stream>>>(whh0, whh0b, HID * HID);
  k_f2b<<<256, 256, 0, stream>>>(wih1, wih1b, HID * HID);
  k_f2b<<<256, 256, 0, stream>>>(whh1, whh1b, HID * HID);
  k_misc<<<4, 256, 0, stream>>>(bih0, bhh0, bih1, bhh1, bias0, bias1, flags, 1024);
  k_latent<<<(2 * BB * HID) / 256, 256, 0, stream>>>(z, l2h_w, l2h_b, h0b);
  k_embed<<<BB * SS, 256, 0, stream>>>(emb, inp, xb);
  k_transpose<<<dim3(VOCAB / 32, HID / 32), dim3(32, 8), 0, stream>>>(predw, predTb);

  size_t gemm_lds = (size_t)2 * 128 * 72 * 2;
  size_t scan_lds = (size_t)32 * 1032 * 2;

  // xw0 = x @ w_ih0^T + (b_ih0 + b_hh0)   -> bf16
  gemm_bt<unsigned short><<<(BB * SS / 128) * (HID / 128), 256, gemm_lds, stream>>>(
      xb, wih0b, bias0, xw0, BB * SS, HID, EMB);
  // layer 0 scan
  k_scan<<<32, 64, scan_lds, stream>>>(whh0b, xw0, h0b, ys0, hping, flags);
  // xw1 = h1 @ w_ih1^T + (b_ih1 + b_hh1)  -> bf16
  gemm_bt<unsigned short><<<(BB * SS / 128) * (HID / 128), 256, gemm_lds, stream>>>(
      ys0, wih1b, bias1, xw1, BB * SS, HID, HID);
  // layer 1 scan
  k_scan<<<32, 64, scan_lds, stream>>>(whh1b, xw1, h0b + BB * HID, ys1, hping, flags + 512);
  // logits = h2 @ pred_w + pred_b  -> fp32 (d_out)
  gemm_bt<float><<<(BB * SS / 128) * (VOCAB / 128), 256, gemm_lds, stream>>>(
      ys1, predTb, predb, out, BB * SS, VOCAB, HID);
}

// Round 5
// 2994.698 us; speedup vs baseline: 3.5254x; 1.6913x over previous
//
#include <hip/hip_runtime.h>
#include <hip/hip_bf16.h>

#define BB 16
#define SS 512
#define VOCAB 32000
#define EMB 512
#define HID 1024
#define LAT 256

typedef __attribute__((ext_vector_type(8))) short bf16x8v;
typedef __attribute__((ext_vector_type(4))) float f32x4v;

__device__ __forceinline__ unsigned short f2b(float f) {
  unsigned int u = __float_as_uint(f);
  unsigned int r = (u + 0x7fffu + ((u >> 16) & 1u)) >> 16;
  return (unsigned short)r;
}

__device__ __forceinline__ float b2f(unsigned short s) {
  return __uint_as_float(((unsigned int)s) << 16);
}

__device__ __forceinline__ float fast_tanh(float x) {
  float t = fminf(fmaxf(x * 2.8853900817779268f, -60.f), 60.f);
  float e = __builtin_amdgcn_exp2f(t);
  return (e - 1.f) * __builtin_amdgcn_rcpf(e + 1.f);
}

// coherent-point 16B load: bypass (possibly stale) L1/L2, read LLC directly.
__device__ __forceinline__ bf16x8v load16_coherent(const unsigned short* p) {
  bf16x8v r;
  asm volatile("global_load_dwordx4 %0, %1, off sc0 sc1"
               : "=v"(r) : "v"(p) : "memory");
  return r;
}

// granular vmem wait + scheduling fence (rule #18)
#define WAITV(n)                                                   \
  do {                                                             \
    asm volatile("s_waitcnt vmcnt(" #n ")" ::: "memory");          \
    __builtin_amdgcn_sched_barrier(0);                             \
  } while (0)

// 8-step MFMA chunk: consume HF[K0..K0+8) against LDS weight row WROW into A
#define MCHUNK(HF, WROW, K0, A)                                              \
  _Pragma("unroll")                                                          \
  for (int kk = K0; kk < K0 + 8; ++kk) {                                     \
    bf16x8v bw = *(const bf16x8v*)&Ws[(WROW) * LDW + kk * 32 + fg * 8];      \
    A = __builtin_amdgcn_mfma_f32_16x16x32_bf16(HF[kk], bw, A, 0, 0, 0);     \
  }

// ---------------- generic fp32 -> bf16 ----------------
__global__ __launch_bounds__(256) void k_f2b(const float* __restrict__ src,
                                             unsigned short* __restrict__ dst, int n) {
  int i = blockIdx.x * 256 + threadIdx.x;
  int stride = gridDim.x * 256;
  for (; i < n; i += stride) dst[i] = f2b(src[i]);
}

// ---------------- biases + flag zeroing ----------------
__global__ __launch_bounds__(256) void k_misc(const float* __restrict__ bih0, const float* __restrict__ bhh0,
                                              const float* __restrict__ bih1, const float* __restrict__ bhh1,
                                              float* __restrict__ bias0, float* __restrict__ bias1,
                                              unsigned int* __restrict__ flags, int nflags) {
  int i = blockIdx.x * 256 + threadIdx.x;
  if (i < HID) { bias0[i] = bih0[i] + bhh0[i]; bias1[i] = bih1[i] + bhh1[i]; }
  if (i < nflags) flags[i] = 0u;
}

// ---------------- hidden = z @ l2h_w + b, torch-reshape to [2][16][1024], bf16 ----------------
__global__ __launch_bounds__(256) void k_latent(const float* __restrict__ z, const float* __restrict__ w,
                                                const float* __restrict__ bvec, unsigned short* __restrict__ h0) {
  int idx = blockIdx.x * 256 + threadIdx.x;          // [0, 2*16*1024)
  int l  = idx >> 14;
  int bb = (idx >> 10) & 15;
  int hh = idx & 1023;
  int b = l * 8 + (bb >> 1);                          // torch flat-reshape mapping
  int j = ((bb & 1) << 10) | hh;
  float s = bvec[j];
  for (int k = 0; k < LAT; ++k) s += z[b * LAT + k] * w[k * (HID * 2) + j];
  h0[idx] = f2b(s);
}

// ---------------- embedding gather -> bf16 ----------------
__global__ __launch_bounds__(256) void k_embed(const float* __restrict__ emb, const int* __restrict__ inp,
                                               unsigned short* __restrict__ x) {
  int row = blockIdx.x;                               // B*S
  int tok = inp[row];
  for (int j = threadIdx.x; j < EMB; j += 256)
    x[(long)row * EMB + j] = f2b(emb[(long)tok * EMB + j]);
}

// ---------------- pred_w [K][N] fp32 -> [N][K] bf16 (tiled transpose) ----------------
__global__ void k_transpose(const float* __restrict__ src, unsigned short* __restrict__ dst) {
  __shared__ float tile[32][33];
  int n0 = blockIdx.x * 32;
  int k0 = blockIdx.y * 32;
  int tx = threadIdx.x, ty = threadIdx.y;
  for (int i = ty; i < 32; i += 8)
    tile[i][tx] = src[(long)(k0 + i) * VOCAB + n0 + tx];
  __syncthreads();
  for (int i = ty; i < 32; i += 8)
    dst[(long)(n0 + i) * HID + k0 + tx] = f2b(tile[tx][i]);
}

// ---------------- C[M][N] = A[M][K] * B[N][K]^T + bias[N]  (bf16 in, OUT out) ----------------
template <typename OUT>
__global__ __launch_bounds__(256) void gemm_bt(const unsigned short* __restrict__ A,
                                               const unsigned short* __restrict__ Bm,
                                               const float* __restrict__ bias,
                                               OUT* __restrict__ C,
                                               int M, int N, int K) {
  const int LDT = 72;                                  // padded LDS K-stride
  extern __shared__ unsigned short smem_g[];
  unsigned short* As = smem_g;
  unsigned short* Bs = smem_g + 128 * LDT;

  int nTn = N >> 7;
  int tm = blockIdx.x / nTn, tn = blockIdx.x % nTn;
  long m0 = (long)tm << 7, n0 = (long)tn << 7;
  int t = threadIdx.x;
  int lane = t & 63, w = t >> 6;
  int wr = (w >> 1) * 64, wc = (w & 1) * 64;
  int fr = lane & 15, fg = lane >> 4;

  f32x4v acc[4][4];
  f32x4v zero = {0.f, 0.f, 0.f, 0.f};
#pragma unroll
  for (int i = 0; i < 4; ++i)
#pragma unroll
    for (int j = 0; j < 4; ++j) acc[i][j] = zero;

  int srow = t >> 3;
  int scol = (t & 7) << 3;

  for (int kt = 0; kt < K; kt += 64) {
#pragma unroll
    for (int it = 0; it < 4; ++it) {
      int row = srow + it * 32;
      bf16x8v va = *(const bf16x8v*)&A[(m0 + row) * K + kt + scol];
      bf16x8v vb = *(const bf16x8v*)&Bm[(n0 + row) * K + kt + scol];
      *(bf16x8v*)&As[row * LDT + scol] = va;
      *(bf16x8v*)&Bs[row * LDT + scol] = vb;
    }
    __syncthreads();
#pragma unroll
    for (int kk = 0; kk < 2; ++kk) {
      int ko = kk * 32 + fg * 8;
      bf16x8v af[4], bfv[4];
#pragma unroll
      for (int i = 0; i < 4; ++i) af[i] = *(const bf16x8v*)&As[(wr + i * 16 + fr) * LDT + ko];
#pragma unroll
      for (int j = 0; j < 4; ++j) bfv[j] = *(const bf16x8v*)&Bs[(wc + j * 16 + fr) * LDT + ko];
#pragma unroll
      for (int i = 0; i < 4; ++i)
#pragma unroll
        for (int j = 0; j < 4; ++j)
          acc[i][j] = __builtin_amdgcn_mfma_f32_16x16x32_bf16(af[i], bfv[j], acc[i][j], 0, 0, 0);
    }
    __syncthreads();
  }

#pragma unroll
  for (int j = 0; j < 4; ++j) {
    long n = n0 + wc + j * 16 + fr;
    float bv = bias[n];
#pragma unroll
    for (int i = 0; i < 4; ++i) {
      long mrow = m0 + wr + i * 16 + fg * 4;
#pragma unroll
      for (int r = 0; r < 4; ++r) {
        float v = acc[i][j][r] + bv;
        if constexpr (__hip_internal::is_same<OUT, float>::value) {
          C[(mrow + r) * (long)N + n] = v;
        } else {
          C[(mrow + r) * (long)N + n] = f2b(v);
        }
      }
    }
  }
}

// ---------------- fused 2-layer pipelined RNN scan ----------------
// 96 WGs x 128 threads (2 waves), persistent. Max 32 in-flight asm loads per wave.
//   WG 0..31  (L0): h1[t] = tanh(xw0[t] + h1[t-1] @ Whh0^T); wave w owns 16 cols.
//   WG 32..95 (L1): h2[t] = tanh(h1[t] @ Wih1^T + h2[t-1] @ Whh1^T + bias1), 16 cols;
//                   wave0 = h1-part (+ epilogue), wave1 = h2-part (partial via LDS).
// Broadcast: relaxed agent-atomic write-through stores; sc0/sc1 bypass loads;
// per-WG flag lines; producer does vmcnt(0) ack before flag store.
__global__ __launch_bounds__(128, 1) void k_scan2(const unsigned short* __restrict__ whh0,
                                                  const unsigned short* __restrict__ wih1,
                                                  const unsigned short* __restrict__ whh1,
                                                  const unsigned short* __restrict__ xw0,   // [B][S][H] bf16 (bias0 folded)
                                                  const float* __restrict__ bias1,
                                                  const unsigned short* __restrict__ h0all, // [2][B][H] bf16
                                                  unsigned short* __restrict__ ys0,         // [B][S][H] bf16
                                                  unsigned short* __restrict__ ys1,         // [B][S][H] bf16
                                                  unsigned int* __restrict__ flags) {       // flag0: [i*16]; flag1: [1024+j*16]
  const int LDW = 1032;                                // pad 8: 2-way bank alias only
  extern __shared__ unsigned short Ws[];
  float* Part = (float*)(Ws + 32 * LDW);               // 64 lanes x f32x4 partial
  const int tid = threadIdx.x;
  const int lane = tid & 63;
  const int wv = tid >> 6;
  const int fr = lane & 15, fg = lane >> 4;
  const int wg = blockIdx.x;
  const f32x4v zero = {0.f, 0.f, 0.f, 0.f};

  if (wg < 32) {
    // ================= Layer 0 =================
    const int nbase = wg * 32;
    for (int c = tid; c < 32 * 128; c += 128) {
      int row = c >> 7, col = (c & 127) << 3;
      *(bf16x8v*)&Ws[row * LDW + col] = *(const bf16x8v*)&whh0[(long)(nbase + row) * HID + col];
    }
    __syncthreads();

    const int wrow = wv * 16 + fr;                     // LDS weight row
    const int mycol = nbase + wrow;                    // output column
    const int odd = fr & 1;

    for (int t = 0; t < SS; ++t) {
      // xw prefetch (independent of h) — overlaps the poll
      unsigned short xv[4];
#pragma unroll
      for (int r = 0; r < 4; ++r)
        xv[r] = xw0[((long)(fg * 4 + r) * SS + t) * HID + mycol];

      if (t > 0) {
        unsigned tgt = (unsigned)t;
        for (;;) {
          unsigned v = 0xffffffffu;
          if (lane < 32)
            v = __hip_atomic_load(&flags[lane << 4], __ATOMIC_RELAXED, __HIP_MEMORY_SCOPE_AGENT);
          if (__all(v >= tgt)) break;
        }
      }
      const unsigned short* hp = (t == 0) ? (h0all + (long)fr * HID)
                                          : (ys0 + ((long)fr * SS + (t - 1)) * HID);
      bf16x8v hf[32];
#pragma unroll
      for (int kk = 0; kk < 32; ++kk) hf[kk] = load16_coherent(&hp[kk * 32 + fg * 8]);
      __builtin_amdgcn_sched_barrier(0);

      f32x4v aA = zero, aB = zero;
      WAITV(24); MCHUNK(hf, wrow, 0,  aA);
      WAITV(16); MCHUNK(hf, wrow, 8,  aB);
      WAITV(8);  MCHUNK(hf, wrow, 16, aA);
      WAITV(0);  MCHUNK(hf, wrow, 24, aB);
      f32x4v acc = aA + aB;

      unsigned av[4], pv[4];
#pragma unroll
      for (int r = 0; r < 4; ++r) {
        av[r] = (unsigned)f2b(fast_tanh(acc[r] + b2f(xv[r])));
        pv[r] = __shfl_xor(av[r], 1);
      }
      if (!odd) {
#pragma unroll
        for (int r = 0; r < 4; ++r)
          __hip_atomic_store((unsigned int*)&ys0[((long)(fg * 4 + r) * SS + t) * HID + mycol],
                             av[r] | (pv[r] << 16), __ATOMIC_RELAXED, __HIP_MEMORY_SCOPE_AGENT);
      }
      WAITV(0);                                        // stores ack'd at coherence point
      __syncthreads();                                 // both waves done
      if (tid == 0)
        __hip_atomic_store(&flags[wg << 4], (unsigned)(t + 1),
                           __ATOMIC_RELAXED, __HIP_MEMORY_SCOPE_AGENT);
    }
  } else {
    // ================= Layer 1 =================
    const int j = wg - 32;
    const int nbase = j * 16;
    for (int c = tid; c < 32 * 128; c += 128) {
      int row = c >> 7, col = (c & 127) << 3;
      const unsigned short* src = (row < 16) ? &wih1[(long)(nbase + row) * HID + col]
                                             : &whh1[(long)(nbase + row - 16) * HID + col];
      *(bf16x8v*)&Ws[row * LDW + col] = *(const bf16x8v*)src;
    }
    __syncthreads();
    const int odd = fr & 1;

    if (wv == 0) {
      // ---- wave0: h1[t] @ Wih1^T + epilogue ----
      const float bv = bias1[nbase + fr];
      for (int t = 0; t < SS; ++t) {
        {
          unsigned tgt = (unsigned)(t + 1);            // L0 finished step t
          for (;;) {
            unsigned v = 0xffffffffu;
            if (lane < 32)
              v = __hip_atomic_load(&flags[lane << 4], __ATOMIC_RELAXED, __HIP_MEMORY_SCOPE_AGENT);
            if (__all(v >= tgt)) break;
          }
        }
        const unsigned short* hp1 = ys0 + ((long)fr * SS + t) * HID;
        bf16x8v hf[32];
#pragma unroll
        for (int kk = 0; kk < 32; ++kk) hf[kk] = load16_coherent(&hp1[kk * 32 + fg * 8]);
        __builtin_amdgcn_sched_barrier(0);

        f32x4v aA = zero, aB = zero;
        WAITV(24); MCHUNK(hf, fr, 0,  aA);
        WAITV(16); MCHUNK(hf, fr, 8,  aB);
        WAITV(8);  MCHUNK(hf, fr, 16, aA);
        WAITV(0);  MCHUNK(hf, fr, 24, aB);

        __syncthreads();                               // wave1's partial is in LDS
        f32x4v part = *(const f32x4v*)&Part[lane << 2];
        f32x4v sum = (aA + aB) + part;

        unsigned av[4], pv[4];
#pragma unroll
        for (int r = 0; r < 4; ++r) {
          av[r] = (unsigned)f2b(fast_tanh(sum[r] + bv));
          pv[r] = __shfl_xor(av[r], 1);
        }
        if (!odd) {
#pragma unroll
          for (int r = 0; r < 4; ++r)
            __hip_atomic_store((unsigned int*)&ys1[((long)(fg * 4 + r) * SS + t) * HID + nbase + fr],
                               av[r] | (pv[r] << 16), __ATOMIC_RELAXED, __HIP_MEMORY_SCOPE_AGENT);
        }
        WAITV(0);                                      // h2 stores ack'd
        if (lane == 0)
          __hip_atomic_store(&flags[1024 + (j << 4)], (unsigned)(t + 1),
                             __ATOMIC_RELAXED, __HIP_MEMORY_SCOPE_AGENT);
      }
    } else {
      // ---- wave1: h2[t-1] @ Whh1^T -> LDS partial ----
      for (int t = 0; t < SS; ++t) {
        if (t > 0) {
          unsigned tgt = (unsigned)t;                  // all L1 WGs finished step t-1
          for (;;) {
            unsigned v = __hip_atomic_load(&flags[1024 + (lane << 4)],
                                           __ATOMIC_RELAXED, __HIP_MEMORY_SCOPE_AGENT);
            if (__all(v >= tgt)) break;
          }
        }
        const unsigned short* hp2 = (t == 0) ? (h0all + (long)(BB + fr) * HID)
                                             : (ys1 + ((long)fr * SS + (t - 1)) * HID);
        bf16x8v hf[32];
#pragma unroll
        for (int kk = 0; kk < 32; ++kk) hf[kk] = load16_coherent(&hp2[kk * 32 + fg * 8]);
        __builtin_amdgcn_sched_barrier(0);

        f32x4v aA = zero, aB = zero;
        WAITV(24); MCHUNK(hf, 16 + fr, 0,  aA);
        WAITV(16); MCHUNK(hf, 16 + fr, 8,  aB);
        WAITV(8);  MCHUNK(hf, 16 + fr, 16, aA);
        WAITV(0);  MCHUNK(hf, 16 + fr, 24, aB);

        *(f32x4v*)&Part[lane << 2] = aA + aB;          // publish partial
        __syncthreads();                               // wave0 consumes after this
      }
    }
  }
}

extern "C" void kernel_launch(void* const* d_in, const int* in_sizes, int n_in,
                              void* d_out, int out_size, void* d_ws, size_t ws_size,
                              hipStream_t stream) {
  const float* z     = (const float*)d_in[0];
  const int*   inp   = (const int*)d_in[1];
  const float* emb   = (const float*)d_in[2];
  const float* l2h_w = (const float*)d_in[3];
  const float* l2h_b = (const float*)d_in[4];
  const float* wih0  = (const float*)d_in[5];
  const float* whh0  = (const float*)d_in[6];
  const float* bih0  = (const float*)d_in[7];
  const float* bhh0  = (const float*)d_in[8];
  const float* wih1  = (const float*)d_in[9];
  const float* whh1  = (const float*)d_in[10];
  const float* bih1  = (const float*)d_in[11];
  const float* bhh1  = (const float*)d_in[12];
  const float* predw = (const float*)d_in[13];
  const float* predb = (const float*)d_in[14];
  float* out = (float*)d_out;

  char* ws = (char*)d_ws;
  size_t off = 0;
  auto alloc = [&](size_t bytes) {
    char* p = ws + off;
    off = (off + bytes + 255) & ~(size_t)255;
    return p;
  };
  unsigned short* xb     = (unsigned short*)alloc((size_t)BB * SS * EMB * 2);
  unsigned short* wih0b  = (unsigned short*)alloc((size_t)HID * EMB * 2);
  unsigned short* whh0b  = (unsigned short*)alloc((size_t)HID * HID * 2);
  unsigned short* wih1b  = (unsigned short*)alloc((size_t)HID * HID * 2);
  unsigned short* whh1b  = (unsigned short*)alloc((size_t)HID * HID * 2);
  unsigned short* predTb = (unsigned short*)alloc((size_t)VOCAB * HID * 2);
  unsigned short* xw0    = (unsigned short*)alloc((size_t)BB * SS * HID * 2);
  unsigned short* ys0    = (unsigned short*)alloc((size_t)BB * SS * HID * 2);
  unsigned short* ys1    = (unsigned short*)alloc((size_t)BB * SS * HID * 2);
  unsigned short* h0b    = (unsigned short*)alloc((size_t)2 * BB * HID * 2);
  float*          bias0  = (float*)alloc((size_t)HID * 4);
  float*          bias1  = (float*)alloc((size_t)HID * 4);
  unsigned int*   flags  = (unsigned int*)alloc((size_t)2048 * 4);  // flag0[32*16] + flag1[64*16]

  // prep
  k_f2b<<<256, 256, 0, stream>>>(wih0, wih0b, HID * EMB);
  k_f2b<<<256, 256, 0, stream>>>(whh0, whh0b, HID * HID);
  k_f2b<<<256, 256, 0, stream>>>(wih1, wih1b, HID * HID);
  k_f2b<<<256, 256, 0, stream>>>(whh1, whh1b, HID * HID);
  k_misc<<<8, 256, 0, stream>>>(bih0, bhh0, bih1, bhh1, bias0, bias1, flags, 2048);
  k_latent<<<(2 * BB * HID) / 256, 256, 0, stream>>>(z, l2h_w, l2h_b, h0b);
  k_embed<<<BB * SS, 256, 0, stream>>>(emb, inp, xb);
  k_transpose<<<dim3(VOCAB / 32, HID / 32), dim3(32, 8), 0, stream>>>(predw, predTb);

  size_t gemm_lds = (size_t)2 * 128 * 72 * 2;
  size_t scan_lds = (size_t)32 * 1032 * 2 + 64 * 4 * 4;  // weights + partial buffer

  // xw0 = x @ w_ih0^T + (b_ih0 + b_hh0)   -> bf16
  gemm_bt<unsigned short><<<(BB * SS / 128) * (HID / 128), 256, gemm_lds, stream>>>(
      xb, wih0b, bias0, xw0, BB * SS, HID, EMB);
  // fused pipelined 2-layer scan
  k_scan2<<<96, 128, scan_lds, stream>>>(whh0b, wih1b, whh1b, xw0, bias1, h0b, ys0, ys1, flags);
  // logits = h2 @ pred_w + pred_b  -> fp32 (d_out)
  gemm_bt<float><<<(BB * SS / 128) * (VOCAB / 128), 256, gemm_lds, stream>>>(
      ys1, predTb, predb, out, BB * SS, VOCAB, HID);
}